// Round 5
// baseline (130.822 us; speedup 1.0000x reference)
//
#include <hip/hip_runtime.h>
#include <hip/hip_bf16.h>

// ContrastiveLoss: N=16384, D=128.
// loss = mean_i log1p(rep_i / (att_i + EPS)), rep_i = mean_j exp(-(sq1_i+sq2_j-2*x_i.y_j))
// att_i = exp(-||x_i - y_i||^2);  TAU=0.5 => 2*TAU = 1.
// exp folded to native exp2: B2 pre-scaled by 2/ln2, sq1/sq2 by 1/ln2; sq1 stored
// NEGATED so the MFMA accumulator can be initialized with -(s1'+s2') and the
// epilogue is exp2(acc) directly (no subs, no clamp -- d <= -200 always for
// this data; underflow to 0 matches the fp32 reference's own underflow).
// Outputs: [loss, mean(att), mean(rep)]  (3 fp32 scalars)

#define EPS 1e-8f
#define D_DIM 128
#define INV_LN2 1.44269504088896f
#define SCALE_B 2.88539008177793f   // 2/ln2
#define NCHUNK 8                    // column chunks (XCD count)
#define TCOLS 64                    // cols per B-tile
#define NT 32                       // B-tiles per chunk (2048 cols)
#define BM 64                       // rows per block

typedef __attribute__((ext_vector_type(8))) short bf16x8;
typedef __attribute__((ext_vector_type(4))) float f32x4;

typedef __attribute__((address_space(1))) const unsigned int gu32_t;
typedef __attribute__((address_space(3))) unsigned int lu32_t;

static __device__ inline void gload_lds16(const void* g, void* l) {
    // 16-byte-per-lane global -> LDS direct copy (wave-uniform LDS base + lane*16)
    __builtin_amdgcn_global_load_lds((gu32_t*)g, (lu32_t*)l, 16, 0, 0);
}

static __device__ inline ushort f2bf(float x) {
    union { __hip_bfloat16 h; ushort u; } cvt;
    cvt.h = __float2bfloat16(x);
    return cvt.u;
}

// 4 waves/block, one row per wave: row norms (log2 domain; sq1 negated),
// attraction, bf16 casts (B2 pre-scaled by 2/ln2).
__global__ __launch_bounds__(256) void prep_kernel(
    const float* __restrict__ X1, const float* __restrict__ X2,
    ushort* __restrict__ B1, ushort* __restrict__ B2,
    float* __restrict__ sq1n, float* __restrict__ sq2,
    float* __restrict__ att)
{
    const int w = threadIdx.x >> 6;
    const int l = threadIdx.x & 63;           // 2 floats each -> 128
    const int i = blockIdx.x * 4 + w;
    const float2 a = ((const float2*)(X1 + (size_t)i * D_DIM))[l];
    const float2 b = ((const float2*)(X2 + (size_t)i * D_DIM))[l];

    ushort2 pa; pa.x = f2bf(a.x);           pa.y = f2bf(a.y);
    ushort2 pb; pb.x = f2bf(b.x * SCALE_B); pb.y = f2bf(b.y * SCALE_B);
    ((ushort2*)(B1 + (size_t)i * D_DIM))[l] = pa;
    ((ushort2*)(B2 + (size_t)i * D_DIM))[l] = pb;

    float s1 = a.x * a.x + a.y * a.y;
    float s2 = b.x * b.x + b.y * b.y;
    float dx = a.x - b.x, dy = a.y - b.y;
    float ps = dx * dx + dy * dy;
    #pragma unroll
    for (int m = 32; m; m >>= 1) {
        s1 += __shfl_xor(s1, m, 64);
        s2 += __shfl_xor(s2, m, 64);
        ps += __shfl_xor(ps, m, 64);
    }
    if (l == 0) {
        sq1n[i] = -s1 * INV_LN2;   // negated log2-domain row norm
        sq2[i]  =  s2 * INV_LN2;
        att[i]  = __expf(-ps);
    }
}

// Fused cross-GEMM + exp2 + row-sum. Block = 64 rows x 2048 cols (32 tiles of
// 64 cols). 4 waves, each owning a 16-col stripe (1 B-frag). A-tile (16KB) in
// registers; B-tiles double-buffered through 2x16KB LDS (prefetch-early /
// barrier-late). acc initialized to -(s1'+s2') so epilogue = exp2(acc) + add.
// Row partials in registers across all tiles; one plain store per (row,stripe)
// into partials[4*NCHUNK][N] -- zero global atomics. LDS XOR swizzle
// byte ^= (row&15)<<4 on ds_read; global_load_lds sources inverse-swizzled.
__global__ __launch_bounds__(256, 4) void cross_kernel(
    const ushort* __restrict__ B1, const ushort* __restrict__ B2,
    const float* __restrict__ sq1n, const float* __restrict__ sq2,
    float* __restrict__ partials, int Ntot)
{
    __shared__ char lds[2][16384];       // B dbuf; buf0 initially stages A
    __shared__ float ldsS1[BM];          // negated scaled row norms

    const int t    = threadIdx.x;
    const int lane = t & 63;
    const int wx   = t >> 6;             // 0..3 col stripe
    const int lr   = lane & 15;
    const int kg   = lane >> 4;          // k-group == C/D row group

    const int brow = blockIdx.y * BM;
    const int ccol = blockIdx.x * (NT * TCOLS);

    const char* gA = (const char*)(B1 + (size_t)brow * D_DIM);   // 16 KB contig
    const char* gB = (const char*)(B2 + (size_t)ccol * D_DIM);

    // ---- stage A -> buf0 and B-tile0 -> buf1 concurrently ----
    #pragma unroll
    for (int it = 0; it < 4; ++it) {
        const unsigned Lb = it * 4096u + wx * 1024u;
        const unsigned L  = Lb + lane * 16u;
        const unsigned src = L ^ (((L >> 8) & 15u) << 4);
        gload_lds16(gA + src, lds[0] + Lb);
        gload_lds16(gB + src, lds[1] + Lb);
    }
    if (t < BM) ldsS1[t] = sq1n[brow + t];
    __syncthreads();   // A, B0, S1 resident

    // ---- A fragments -> registers (held for whole kernel) ----
    bf16x8 aR[16];     // [m][kc] flattened m*4+kc
    #pragma unroll
    for (int m = 0; m < 4; ++m) {
        const int row = m * 16 + lr;
        #pragma unroll
        for (int kc = 0; kc < 4; ++kc) {
            const unsigned addr = (unsigned)(row * 256 + kc * 64 + kg * 16)
                                  ^ ((unsigned)lr << 4);
            aR[m * 4 + kc] = *(const bf16x8*)(lds[0] + addr);
        }
    }
    __syncthreads();   // buf0 free for B-tile 1 prefetch

    float p[4][4];     // row partials across ALL tiles
    #pragma unroll
    for (int m = 0; m < 4; ++m)
        #pragma unroll
        for (int r = 0; r < 4; ++r)
            p[m][r] = 0.f;

    float s2c = sq2[ccol + wx * 16 + lr];   // this stripe's col norm, tile 0

    for (int tt = 0; tt < NT; ++tt) {
        // prefetch next B-tile into the buffer just freed
        if (tt < NT - 1) {
            const char* gBn = (const char*)(B2 + (size_t)(ccol + (tt + 1) * TCOLS) * D_DIM);
            char* dst = lds[tt & 1];
            #pragma unroll
            for (int it = 0; it < 4; ++it) {
                const unsigned Lb = it * 4096u + wx * 1024u;
                const unsigned L  = Lb + lane * 16u;
                const unsigned src = L ^ (((L >> 8) & 15u) << 4);
                gload_lds16(gBn + src, dst + Lb);
            }
        }
        const char* cur = lds[(tt + 1) & 1];

        // pipeline next tile's col-norm load
        const float s2n = (tt < NT - 1)
            ? sq2[ccol + (tt + 1) * TCOLS + wx * 16 + lr] : 0.f;

        // ---- acc init = -(s1' + s2') ----
        f32x4 acc[4];
        #pragma unroll
        for (int m = 0; m < 4; ++m) {
            const float4 ns1v = *(const float4*)(ldsS1 + m * 16 + kg * 4);
            acc[m] = (f32x4){ns1v.x - s2c, ns1v.y - s2c,
                             ns1v.z - s2c, ns1v.w - s2c};
        }

        // ---- MFMA: K=128 in 4 chunks, 1 B-frag per chunk ----
        #pragma unroll
        for (int kc = 0; kc < 4; ++kc) {
            const int row = wx * 16 + lr;
            const unsigned addr = (unsigned)(row * 256 + kc * 64 + kg * 16)
                                  ^ ((unsigned)lr << 4);
            const bf16x8 bF = *(const bf16x8*)(cur + addr);
            #pragma unroll
            for (int m = 0; m < 4; ++m)
                acc[m] = __builtin_amdgcn_mfma_f32_16x16x32_bf16(
                    aR[m * 4 + kc], bF, acc[m], 0, 0, 0);
        }

        // ---- epilogue: p += exp2(acc) ----
        // C/D layout (16x16x32): col = lr, row = kg*4 + r
        #pragma unroll
        for (int m = 0; m < 4; ++m)
            #pragma unroll
            for (int r = 0; r < 4; ++r)
                p[m][r] += __builtin_amdgcn_exp2f(acc[m][r]);

        s2c = s2n;
        __syncthreads();   // drains prefetch + buffer swap
    }

    // ---- reduce partials over the 16 col-lanes; one store per (row, wx) ----
    const size_t plane = (size_t)(blockIdx.x * 4 + wx) * (size_t)Ntot;
    #pragma unroll
    for (int m = 0; m < 4; ++m) {
        #pragma unroll
        for (int r = 0; r < 4; ++r) {
            float v = p[m][r];
            v += __shfl_xor(v, 1, 64);
            v += __shfl_xor(v, 2, 64);
            v += __shfl_xor(v, 4, 64);
            v += __shfl_xor(v, 8, 64);
            if (lr == 0)
                partials[plane + brow + m * 16 + kg * 4 + r] = v;
        }
    }
}

// Sum the 4*NCHUNK partial planes per row.
__global__ __launch_bounds__(256) void rowsum_kernel(
    const float* __restrict__ partials, float* __restrict__ rep, int N)
{
    const int i = blockIdx.x * 256 + threadIdx.x;
    float s = 0.f;
    #pragma unroll
    for (int pl = 0; pl < 4 * NCHUNK; ++pl)
        s += partials[(size_t)pl * N + i];
    rep[i] = s;
}

// Final: loss = mean log1p((rep_i/N)/(att_i+EPS)), mean att, mean rep/N.
__global__ __launch_bounds__(256) void final_kernel(
    const float* __restrict__ rep, const float* __restrict__ att,
    float* __restrict__ out, int N)
{
    __shared__ float sm[3][4];
    const float inv = 1.0f / (float)N;
    float ls = 0.f, sa = 0.f, sr = 0.f;
    for (int i = threadIdx.x; i < N; i += 256) {
        const float rp = rep[i] * inv;
        const float at = att[i];
        ls += log1pf(rp / (at + EPS));
        sa += at;
        sr += rp;
    }
    #pragma unroll
    for (int m = 32; m; m >>= 1) {
        ls += __shfl_xor(ls, m, 64);
        sa += __shfl_xor(sa, m, 64);
        sr += __shfl_xor(sr, m, 64);
    }
    const int wid = threadIdx.x >> 6, lane = threadIdx.x & 63;
    if (lane == 0) { sm[0][wid] = ls; sm[1][wid] = sa; sm[2][wid] = sr; }
    __syncthreads();
    if (threadIdx.x == 0) {
        float L = 0.f, A = 0.f, R = 0.f;
        #pragma unroll
        for (int w = 0; w < 4; ++w) { L += sm[0][w]; A += sm[1][w]; R += sm[2][w]; }
        out[0] = L * inv;
        out[1] = A * inv;
        out[2] = R * inv;
    }
}

extern "C" void kernel_launch(void* const* d_in, const int* in_sizes, int n_in,
                              void* d_out, int out_size, void* d_ws, size_t ws_size,
                              hipStream_t stream)
{
    const float* X1 = (const float*)d_in[0];
    const float* X2 = (const float*)d_in[1];
    const int N = in_sizes[0] / D_DIM;   // 16384
    float* out = (float*)d_out;

    char* ws = (char*)d_ws;
    ushort* B1 = (ushort*)ws;                                  // N*128*2 B
    ushort* B2 = (ushort*)(ws + (size_t)N * D_DIM * 2);        // N*128*2 B
    float* sq1n = (float*)(ws + (size_t)N * D_DIM * 4);
    float* sq2 = sq1n + N;
    float* att = sq2 + N;
    float* rep = att + N;
    float* partials = rep + N;   // [4*NCHUNK][N] = 2 MB
    // total ws use: N*512 + 16*N + 4*NCHUNK*N*4 ~= 10.4 MB

    prep_kernel<<<N / 4, 256, 0, stream>>>(X1, X2, B1, B2, sq1n, sq2, att);
    dim3 grid(NCHUNK, N / BM);
    cross_kernel<<<grid, 256, 0, stream>>>(B1, B2, sq1n, sq2, partials, N);
    rowsum_kernel<<<N / 256, 256, 0, stream>>>(partials, rep, N);
    final_kernel<<<1, 256, 0, stream>>>(rep, att, out, N);
}

// Round 6
// 122.839 us; speedup vs baseline: 1.0650x; 1.0650x over previous
//
#include <hip/hip_runtime.h>
#include <hip/hip_bf16.h>

// ContrastiveLoss: N=16384, D=128.
// loss = mean_i log1p(rep_i / (att_i + EPS)), rep_i = mean_j exp(-(sq1_i+sq2_j-2*x_i.y_j))
// att_i = exp(-||x_i - y_i||^2);  TAU=0.5 => 2*TAU = 1.
// exp folded to native exp2: B2 pre-scaled by 2/ln2, sq1/sq2 by 1/ln2; sq1 stored
// NEGATED so the MFMA accumulator is initialized with -(s1'+s2') and the
// epilogue is p += exp2(acc) directly (d <= -100 always for this data; fp32
// underflow to 0 matches the fp32 reference's own underflow).
// Outputs: [loss, mean(att), mean(rep)]  (3 fp32 scalars)

#define EPS 1e-8f
#define D_DIM 128
#define INV_LN2 1.44269504088896f
#define SCALE_B 2.88539008177793f   // 2/ln2
#define NCHUNK 8                    // column chunks (XCD count)
#define TCOLS 64                    // cols per B-tile
#define NT 32                       // B-tiles per chunk (2048 cols)
#define BM 128                      // rows per block

typedef __attribute__((ext_vector_type(8))) short bf16x8;
typedef __attribute__((ext_vector_type(4))) float f32x4;

typedef __attribute__((address_space(1))) const unsigned int gu32_t;
typedef __attribute__((address_space(3))) unsigned int lu32_t;

static __device__ inline void gload_lds16(const void* g, void* l) {
    // 16-byte-per-lane global -> LDS direct copy (wave-uniform LDS base + lane*16)
    __builtin_amdgcn_global_load_lds((gu32_t*)g, (lu32_t*)l, 16, 0, 0);
}

static __device__ inline ushort f2bf(float x) {
    union { __hip_bfloat16 h; ushort u; } cvt;
    cvt.h = __float2bfloat16(x);
    return cvt.u;
}

// 4 waves/block, one row per wave: row norms (log2 domain; sq1 negated),
// attraction, bf16 casts (B2 pre-scaled by 2/ln2).
__global__ __launch_bounds__(256) void prep_kernel(
    const float* __restrict__ X1, const float* __restrict__ X2,
    ushort* __restrict__ B1, ushort* __restrict__ B2,
    float* __restrict__ sq1n, float* __restrict__ sq2,
    float* __restrict__ att)
{
    const int w = threadIdx.x >> 6;
    const int l = threadIdx.x & 63;           // 2 floats each -> 128
    const int i = blockIdx.x * 4 + w;
    const float2 a = ((const float2*)(X1 + (size_t)i * D_DIM))[l];
    const float2 b = ((const float2*)(X2 + (size_t)i * D_DIM))[l];

    ushort2 pa; pa.x = f2bf(a.x);           pa.y = f2bf(a.y);
    ushort2 pb; pb.x = f2bf(b.x * SCALE_B); pb.y = f2bf(b.y * SCALE_B);
    ((ushort2*)(B1 + (size_t)i * D_DIM))[l] = pa;
    ((ushort2*)(B2 + (size_t)i * D_DIM))[l] = pb;

    float s1 = a.x * a.x + a.y * a.y;
    float s2 = b.x * b.x + b.y * b.y;
    float dx = a.x - b.x, dy = a.y - b.y;
    float ps = dx * dx + dy * dy;
    #pragma unroll
    for (int m = 32; m; m >>= 1) {
        s1 += __shfl_xor(s1, m, 64);
        s2 += __shfl_xor(s2, m, 64);
        ps += __shfl_xor(ps, m, 64);
    }
    if (l == 0) {
        sq1n[i] = -s1 * INV_LN2;   // negated log2-domain row norm
        sq2[i]  =  s2 * INV_LN2;
        att[i]  = __expf(-ps);
    }
}

// Fused cross-GEMM + exp2 + row-sum. Block = 128 rows x 2048 cols (32 tiles of
// 64 cols), 512 threads = 8 waves (2 row-halves x 4 col-stripes). A-tile held
// in registers per wave (64 rows); B-tiles flow through a TRIPLE-buffered
// 3x16KB LDS ring with prefetch depth 2 and counted s_waitcnt vmcnt(2) + raw
// s_barrier per iteration (T3+T4: loads stay in flight across barriers; never
// drain to 0 in the main loop). sq2 chunk staged to LDS once so in-loop VMEM
// is exactly the 2 prefetch global_load_lds per wave -> vmcnt count is exact.
// acc init = -(s1'+s2'); epilogue = p += exp2(acc). Row partials in registers;
// one plain store per (row,stripe) -> partials[4*NCHUNK][N]; zero atomics.
// LDS XOR swizzle byte ^= (row&15)<<4 on ds_read; gload sources inv-swizzled.
__global__ __launch_bounds__(512, 4) void cross_kernel(
    const ushort* __restrict__ B1, const ushort* __restrict__ B2,
    const float* __restrict__ sq1n, const float* __restrict__ sq2,
    float* __restrict__ partials, int Ntot)
{
    __shared__ char  bufs[3][16384];     // B-tile ring; bufs[0..1] stage A first
    __shared__ float ldsS1[BM];          // negated scaled row norms
    __shared__ float ldsS2[NT * TCOLS];  // scaled col norms for whole chunk (8 KB)

    const int t    = threadIdx.x;
    const int lane = t & 63;
    const int wid  = t >> 6;             // 0..7
    const int wy   = wid >> 2;           // 0..1 row half
    const int wx   = wid & 3;            // 0..3 col stripe
    const int lr   = lane & 15;
    const int kg   = lane >> 4;          // k-group == C/D row group

    const int brow = blockIdx.y * BM;
    const int ccol = blockIdx.x * (NT * TCOLS);

    const char* gA = (const char*)(B1 + (size_t)brow * D_DIM);   // 32 KB contig
    const char* gB = (const char*)(B2 + (size_t)ccol * D_DIM);

    // ---- prologue staging: A (32 KB -> bufs[0..1]) + B tile0 -> bufs[2] ----
    #pragma unroll
    for (int it = 0; it < 4; ++it) {
        const unsigned Lg   = it * 8192u + wid * 1024u;   // 0..31744, 1KB-aligned
        const unsigned half = Lg >> 14;                   // 0 or 1
        const unsigned Lloc = Lg & 16383u;
        const unsigned L    = Lloc + lane * 16u;
        const unsigned src  = L ^ (((L >> 8) & 15u) << 4);
        gload_lds16(gA + (half << 14) + src, bufs[half] + Lloc);
    }
    #pragma unroll
    for (int it = 0; it < 2; ++it) {
        const unsigned Lb  = it * 8192u + wid * 1024u;
        const unsigned L   = Lb + lane * 16u;
        const unsigned src = L ^ (((L >> 8) & 15u) << 4);
        gload_lds16(gB + src, bufs[2] + Lb);
    }
    if (t < BM) ldsS1[t] = sq1n[brow + t];
    ((float4*)ldsS2)[t] = ((const float4*)(sq2 + ccol))[t];   // 512*16B = 8 KB
    __syncthreads();   // drains all prologue loads (vmcnt(0) OK here)

    // ---- A fragments -> registers (held for whole kernel) ----
    bf16x8 aR[16];     // [m][kc] flattened m*4+kc; 64 rows of this wave's half
    #pragma unroll
    for (int m = 0; m < 4; ++m) {
        const int row = m * 16 + lr;     // local row within the 16KB half
        #pragma unroll
        for (int kc = 0; kc < 4; ++kc) {
            const unsigned addr = (unsigned)(row * 256 + kc * 64 + kg * 16)
                                  ^ ((unsigned)lr << 4);
            aR[m * 4 + kc] = *(const bf16x8*)(bufs[wy] + addr);
        }
    }
    __syncthreads();   // all waves done with bufs[0..1]: ring is free

    // ---- prefetch tile 1 -> bufs[0] (2 loads/wave) ----
    {
        const char* gB1 = (const char*)(B2 + (size_t)(ccol + TCOLS) * D_DIM);
        #pragma unroll
        for (int it = 0; it < 2; ++it) {
            const unsigned Lb  = it * 8192u + wid * 1024u;
            const unsigned L   = Lb + lane * 16u;
            const unsigned src = L ^ (((L >> 8) & 15u) << 4);
            gload_lds16(gB1 + src, bufs[0] + Lb);
        }
    }

    float p[4][4];     // row partials across ALL tiles
    #pragma unroll
    for (int m = 0; m < 4; ++m)
        #pragma unroll
        for (int r = 0; r < 4; ++r)
            p[m][r] = 0.f;

    char* cur = bufs[2];   // tile tt
    char* nx1 = bufs[0];   // tile tt+1 (in flight)
    char* nx2 = bufs[1];   // free: prefetch target for tile tt+2

    for (int tt = 0; tt < NT; ++tt) {
        // issue prefetch of tile tt+2 (2 global_load_lds per wave)
        if (tt + 2 < NT) {
            const char* gBn = (const char*)(B2 + (size_t)(ccol + (tt + 2) * TCOLS) * D_DIM);
            #pragma unroll
            for (int it = 0; it < 2; ++it) {
                const unsigned Lb  = it * 8192u + wid * 1024u;
                const unsigned L   = Lb + lane * 16u;
                const unsigned src = L ^ (((L >> 8) & 15u) << 4);
                gload_lds16(gBn + src, nx2 + Lb);
            }
        }

        const float s2c = ldsS2[tt * TCOLS + wx * 16 + lr];

        // acc init = -(s1' + s2')
        f32x4 acc[4];
        #pragma unroll
        for (int m = 0; m < 4; ++m) {
            const float4 ns1v = *(const float4*)(ldsS1 + wy * 64 + m * 16 + kg * 4);
            acc[m] = (f32x4){ns1v.x - s2c, ns1v.y - s2c,
                             ns1v.z - s2c, ns1v.w - s2c};
        }

        // MFMA: K=128 in 4 chunks, 1 B-frag per chunk
        __builtin_amdgcn_s_setprio(1);
        #pragma unroll
        for (int kc = 0; kc < 4; ++kc) {
            const int row = wx * 16 + lr;
            const unsigned addr = (unsigned)(row * 256 + kc * 64 + kg * 16)
                                  ^ ((unsigned)lr << 4);
            const bf16x8 bF = *(const bf16x8*)(cur + addr);
            #pragma unroll
            for (int m = 0; m < 4; ++m)
                acc[m] = __builtin_amdgcn_mfma_f32_16x16x32_bf16(
                    aR[m * 4 + kc], bF, acc[m], 0, 0, 0);
        }
        __builtin_amdgcn_s_setprio(0);

        // epilogue: p += exp2(acc).  C/D layout: col = lr, row = kg*4 + r
        #pragma unroll
        for (int m = 0; m < 4; ++m)
            #pragma unroll
            for (int r = 0; r < 4; ++r)
                p[m][r] += __builtin_amdgcn_exp2f(acc[m][r]);

        // counted drain: tile tt+1's 2 loads done, tile tt+2's 2 stay in flight
        if (tt < NT - 2) {
            asm volatile("s_waitcnt vmcnt(2)" ::: "memory");
        } else {
            asm volatile("s_waitcnt vmcnt(0)" ::: "memory");
        }
        __builtin_amdgcn_s_barrier();
        __builtin_amdgcn_sched_barrier(0);

        char* tmp = cur; cur = nx1; nx1 = nx2; nx2 = tmp;   // rotate ring
    }

    // ---- reduce partials over the 16 col-lanes; one store per (row, wx) ----
    const size_t plane = (size_t)(blockIdx.x * 4 + wx) * (size_t)Ntot;
    #pragma unroll
    for (int m = 0; m < 4; ++m) {
        #pragma unroll
        for (int r = 0; r < 4; ++r) {
            float v = p[m][r];
            v += __shfl_xor(v, 1, 64);
            v += __shfl_xor(v, 2, 64);
            v += __shfl_xor(v, 4, 64);
            v += __shfl_xor(v, 8, 64);
            if (lr == 0)
                partials[plane + brow + wy * 64 + m * 16 + kg * 4 + r] = v;
        }
    }
}

// Sum the 4*NCHUNK partial planes per row.
__global__ __launch_bounds__(256) void rowsum_kernel(
    const float* __restrict__ partials, float* __restrict__ rep, int N)
{
    const int i = blockIdx.x * 256 + threadIdx.x;
    float s = 0.f;
    #pragma unroll
    for (int pl = 0; pl < 4 * NCHUNK; ++pl)
        s += partials[(size_t)pl * N + i];
    rep[i] = s;
}

// Final: loss = mean log1p((rep_i/N)/(att_i+EPS)), mean att, mean rep/N.
__global__ __launch_bounds__(256) void final_kernel(
    const float* __restrict__ rep, const float* __restrict__ att,
    float* __restrict__ out, int N)
{
    __shared__ float sm[3][4];
    const float inv = 1.0f / (float)N;
    float ls = 0.f, sa = 0.f, sr = 0.f;
    for (int i = threadIdx.x; i < N; i += 256) {
        const float rp = rep[i] * inv;
        const float at = att[i];
        ls += log1pf(rp / (at + EPS));
        sa += at;
        sr += rp;
    }
    #pragma unroll
    for (int m = 32; m; m >>= 1) {
        ls += __shfl_xor(ls, m, 64);
        sa += __shfl_xor(sa, m, 64);
        sr += __shfl_xor(sr, m, 64);
    }
    const int wid = threadIdx.x >> 6, lane = threadIdx.x & 63;
    if (lane == 0) { sm[0][wid] = ls; sm[1][wid] = sa; sm[2][wid] = sr; }
    __syncthreads();
    if (threadIdx.x == 0) {
        float L = 0.f, A = 0.f, R = 0.f;
        #pragma unroll
        for (int w = 0; w < 4; ++w) { L += sm[0][w]; A += sm[1][w]; R += sm[2][w]; }
        out[0] = L * inv;
        out[1] = A * inv;
        out[2] = R * inv;
    }
}

extern "C" void kernel_launch(void* const* d_in, const int* in_sizes, int n_in,
                              void* d_out, int out_size, void* d_ws, size_t ws_size,
                              hipStream_t stream)
{
    const float* X1 = (const float*)d_in[0];
    const float* X2 = (const float*)d_in[1];
    const int N = in_sizes[0] / D_DIM;   // 16384
    float* out = (float*)d_out;

    char* ws = (char*)d_ws;
    ushort* B1 = (ushort*)ws;                                  // N*128*2 B
    ushort* B2 = (ushort*)(ws + (size_t)N * D_DIM * 2);        // N*128*2 B
    float* sq1n = (float*)(ws + (size_t)N * D_DIM * 4);
    float* sq2 = sq1n + N;
    float* att = sq2 + N;
    float* rep = att + N;
    float* partials = rep + N;   // [4*NCHUNK][N] = 2 MB
    // total ws use: N*512 + 16*N + 4*NCHUNK*N*4 ~= 10.4 MB

    prep_kernel<<<N / 4, 256, 0, stream>>>(X1, X2, B1, B2, sq1n, sq2, att);
    dim3 grid(NCHUNK, N / BM);
    cross_kernel<<<grid, 512, 0, stream>>>(B1, B2, sq1n, sq2, partials, N);
    rowsum_kernel<<<N / 256, 256, 0, stream>>>(partials, rep, N);
    final_kernel<<<1, 256, 0, stream>>>(rep, att, out, N);
}

// Round 7
// 85.809 us; speedup vs baseline: 1.5246x; 1.4315x over previous
//
#include <hip/hip_runtime.h>
#include <hip/hip_bf16.h>

// ContrastiveLoss: N=16384, D=128.
// loss = mean_i log1p(rep_i / (att_i + EPS)), rep_i = mean_j exp(-(sq1_i+sq2_j-2*x_i.y_j))
// att_i = exp(-||x_i - y_i||^2);  TAU=0.5 => 2*TAU = 1.
// exp folded to native exp2: B2 pre-scaled by 2/ln2, sq1/sq2 by 1/ln2; sq1 stored
// NEGATED so the MFMA accumulator is initialized with -(s1'+s2') and the
// epilogue is p += exp2(acc). Underflow guard: exp2f(x) == 0.0f (incl.
// subnormal range) for x < -149; for this data acc ~ -370 +- 45, so the
// transcendental block is skipped for essentially every tile (exact, not
// approximate: skipped values are exactly 0 in fp32).
// Outputs: [loss, mean(att), mean(rep)]  (3 fp32 scalars)

#define EPS 1e-8f
#define D_DIM 128
#define INV_LN2 1.44269504088896f
#define SCALE_B 2.88539008177793f   // 2/ln2
#define NCHUNK 8                    // column chunks (XCD count)
#define TCOLS 64                    // cols per B-tile
#define NT 32                       // B-tiles per chunk (2048 cols)
#define BM 128                      // rows per block

typedef __attribute__((ext_vector_type(8))) short bf16x8;
typedef __attribute__((ext_vector_type(4))) float f32x4;

typedef __attribute__((address_space(1))) const unsigned int gu32_t;
typedef __attribute__((address_space(3))) unsigned int lu32_t;

static __device__ inline void gload_lds16(const void* g, void* l) {
    // 16-byte-per-lane global -> LDS direct copy (wave-uniform LDS base + lane*16)
    __builtin_amdgcn_global_load_lds((gu32_t*)g, (lu32_t*)l, 16, 0, 0);
}

static __device__ inline ushort f2bf(float x) {
    union { __hip_bfloat16 h; ushort u; } cvt;
    cvt.h = __float2bfloat16(x);
    return cvt.u;
}

// 4 waves/block, one row per wave: row norms (log2 domain; sq1 negated),
// attraction, bf16 casts (B2 pre-scaled by 2/ln2).
__global__ __launch_bounds__(256) void prep_kernel(
    const float* __restrict__ X1, const float* __restrict__ X2,
    ushort* __restrict__ B1, ushort* __restrict__ B2,
    float* __restrict__ sq1n, float* __restrict__ sq2,
    float* __restrict__ att)
{
    const int w = threadIdx.x >> 6;
    const int l = threadIdx.x & 63;           // 2 floats each -> 128
    const int i = blockIdx.x * 4 + w;
    const float2 a = ((const float2*)(X1 + (size_t)i * D_DIM))[l];
    const float2 b = ((const float2*)(X2 + (size_t)i * D_DIM))[l];

    ushort2 pa; pa.x = f2bf(a.x);           pa.y = f2bf(a.y);
    ushort2 pb; pb.x = f2bf(b.x * SCALE_B); pb.y = f2bf(b.y * SCALE_B);
    ((ushort2*)(B1 + (size_t)i * D_DIM))[l] = pa;
    ((ushort2*)(B2 + (size_t)i * D_DIM))[l] = pb;

    float s1 = a.x * a.x + a.y * a.y;
    float s2 = b.x * b.x + b.y * b.y;
    float dx = a.x - b.x, dy = a.y - b.y;
    float ps = dx * dx + dy * dy;
    #pragma unroll
    for (int m = 32; m; m >>= 1) {
        s1 += __shfl_xor(s1, m, 64);
        s2 += __shfl_xor(s2, m, 64);
        ps += __shfl_xor(ps, m, 64);
    }
    if (l == 0) {
        sq1n[i] = -s1 * INV_LN2;   // negated log2-domain row norm
        sq2[i]  =  s2 * INV_LN2;
        att[i]  = __expf(-ps);
    }
}

// Fused cross-GEMM + exp2 + row-sum. Block = 128 rows x 2048 cols (32 tiles of
// 64 cols), 512 threads = 8 waves (2 row-halves x 4 col-stripes). A-tile held
// in registers per wave (64 rows); B-tiles flow through a TRIPLE-buffered
// 3x16KB LDS ring with prefetch depth 2 and counted s_waitcnt vmcnt(2) + raw
// s_barrier per iteration (T3+T4). sq2 chunk staged to LDS once so in-loop
// VMEM is exactly the 2 prefetch global_load_lds per wave. acc init =
// -(s1'+s2'); epilogue = underflow-guarded p += exp2(acc). Row partials in
// registers; one plain store per (row,stripe) -> partials; zero atomics.
// LDS XOR swizzle byte ^= (row&15)<<4 on ds_read; gload sources inv-swizzled.
__global__ __launch_bounds__(512, 4) void cross_kernel(
    const ushort* __restrict__ B1, const ushort* __restrict__ B2,
    const float* __restrict__ sq1n, const float* __restrict__ sq2,
    float* __restrict__ partials, int Ntot)
{
    __shared__ char  bufs[3][16384];     // B-tile ring; bufs[0..1] stage A first
    __shared__ float ldsS1[BM];          // negated scaled row norms
    __shared__ float ldsS2[NT * TCOLS];  // scaled col norms for whole chunk (8 KB)

    const int t    = threadIdx.x;
    const int lane = t & 63;
    const int wid  = t >> 6;             // 0..7
    const int wy   = wid >> 2;           // 0..1 row half
    const int wx   = wid & 3;            // 0..3 col stripe
    const int lr   = lane & 15;
    const int kg   = lane >> 4;          // k-group == C/D row group

    const int brow = blockIdx.y * BM;
    const int ccol = blockIdx.x * (NT * TCOLS);

    const char* gA = (const char*)(B1 + (size_t)brow * D_DIM);   // 32 KB contig
    const char* gB = (const char*)(B2 + (size_t)ccol * D_DIM);

    // ---- prologue staging: A (32 KB -> bufs[0..1]) + B tile0 -> bufs[2] ----
    #pragma unroll
    for (int it = 0; it < 4; ++it) {
        const unsigned Lg   = it * 8192u + wid * 1024u;   // 0..31744, 1KB-aligned
        const unsigned half = Lg >> 14;                   // 0 or 1
        const unsigned Lloc = Lg & 16383u;
        const unsigned L    = Lloc + lane * 16u;
        const unsigned src  = L ^ (((L >> 8) & 15u) << 4);
        gload_lds16(gA + (half << 14) + src, bufs[half] + Lloc);
    }
    #pragma unroll
    for (int it = 0; it < 2; ++it) {
        const unsigned Lb  = it * 8192u + wid * 1024u;
        const unsigned L   = Lb + lane * 16u;
        const unsigned src = L ^ (((L >> 8) & 15u) << 4);
        gload_lds16(gB + src, bufs[2] + Lb);
    }
    if (t < BM) ldsS1[t] = sq1n[brow + t];
    ((float4*)ldsS2)[t] = ((const float4*)(sq2 + ccol))[t];   // 512*16B = 8 KB
    __syncthreads();   // drains all prologue loads (vmcnt(0) OK here)

    // ---- A fragments -> registers (held for whole kernel) ----
    bf16x8 aR[16];     // [m][kc] flattened m*4+kc; 64 rows of this wave's half
    #pragma unroll
    for (int m = 0; m < 4; ++m) {
        const int row = m * 16 + lr;     // local row within the 16KB half
        #pragma unroll
        for (int kc = 0; kc < 4; ++kc) {
            const unsigned addr = (unsigned)(row * 256 + kc * 64 + kg * 16)
                                  ^ ((unsigned)lr << 4);
            aR[m * 4 + kc] = *(const bf16x8*)(bufs[wy] + addr);
        }
    }
    __syncthreads();   // all waves done with bufs[0..1]: ring is free

    // ---- prefetch tile 1 -> bufs[0] (2 loads/wave) ----
    {
        const char* gB1 = (const char*)(B2 + (size_t)(ccol + TCOLS) * D_DIM);
        #pragma unroll
        for (int it = 0; it < 2; ++it) {
            const unsigned Lb  = it * 8192u + wid * 1024u;
            const unsigned L   = Lb + lane * 16u;
            const unsigned src = L ^ (((L >> 8) & 15u) << 4);
            gload_lds16(gB1 + src, bufs[0] + Lb);
        }
    }

    float p[4][4];     // row partials across ALL tiles
    #pragma unroll
    for (int m = 0; m < 4; ++m)
        #pragma unroll
        for (int r = 0; r < 4; ++r)
            p[m][r] = 0.f;

    char* cur = bufs[2];   // tile tt
    char* nx1 = bufs[0];   // tile tt+1 (in flight)
    char* nx2 = bufs[1];   // free: prefetch target for tile tt+2

    for (int tt = 0; tt < NT; ++tt) {
        // issue prefetch of tile tt+2 (2 global_load_lds per wave)
        if (tt + 2 < NT) {
            const char* gBn = (const char*)(B2 + (size_t)(ccol + (tt + 2) * TCOLS) * D_DIM);
            #pragma unroll
            for (int it = 0; it < 2; ++it) {
                const unsigned Lb  = it * 8192u + wid * 1024u;
                const unsigned L   = Lb + lane * 16u;
                const unsigned src = L ^ (((L >> 8) & 15u) << 4);
                gload_lds16(gBn + src, nx2 + Lb);
            }
        }

        const float s2c = ldsS2[tt * TCOLS + wx * 16 + lr];

        // acc init = -(s1' + s2')
        f32x4 acc[4];
        #pragma unroll
        for (int m = 0; m < 4; ++m) {
            const float4 ns1v = *(const float4*)(ldsS1 + wy * 64 + m * 16 + kg * 4);
            acc[m] = (f32x4){ns1v.x - s2c, ns1v.y - s2c,
                             ns1v.z - s2c, ns1v.w - s2c};
        }

        // MFMA: K=128 in 4 chunks, 1 B-frag per chunk
        __builtin_amdgcn_s_setprio(1);
        #pragma unroll
        for (int kc = 0; kc < 4; ++kc) {
            const int row = wx * 16 + lr;
            const unsigned addr = (unsigned)(row * 256 + kc * 64 + kg * 16)
                                  ^ ((unsigned)lr << 4);
            const bf16x8 bF = *(const bf16x8*)(cur + addr);
            #pragma unroll
            for (int m = 0; m < 4; ++m)
                acc[m] = __builtin_amdgcn_mfma_f32_16x16x32_bf16(
                    aR[m * 4 + kc], bF, acc[m], 0, 0, 0);
        }
        __builtin_amdgcn_s_setprio(0);

        // ---- underflow-guarded epilogue ----
        // exp2f(x) == 0.0f exactly for x < -149 (below subnormal range).
        // C/D layout: col = lr, row = kg*4 + r
        float mxa = fmaxf(fmaxf(acc[0][0], acc[0][1]), fmaxf(acc[0][2], acc[0][3]));
        float mxb = fmaxf(fmaxf(acc[1][0], acc[1][1]), fmaxf(acc[1][2], acc[1][3]));
        float mxc = fmaxf(fmaxf(acc[2][0], acc[2][1]), fmaxf(acc[2][2], acc[2][3]));
        float mxd = fmaxf(fmaxf(acc[3][0], acc[3][1]), fmaxf(acc[3][2], acc[3][3]));
        const float mx = fmaxf(fmaxf(mxa, mxb), fmaxf(mxc, mxd));
        if (__any(mx > -149.0f)) {
            #pragma unroll
            for (int m = 0; m < 4; ++m)
                #pragma unroll
                for (int r = 0; r < 4; ++r)
                    p[m][r] += __builtin_amdgcn_exp2f(acc[m][r]);
        }

        // counted drain: tile tt+1's 2 loads done, tile tt+2's 2 stay in flight
        if (tt < NT - 2) {
            asm volatile("s_waitcnt vmcnt(2)" ::: "memory");
        } else {
            asm volatile("s_waitcnt vmcnt(0)" ::: "memory");
        }
        __builtin_amdgcn_s_barrier();
        __builtin_amdgcn_sched_barrier(0);

        char* tmp = cur; cur = nx1; nx1 = nx2; nx2 = tmp;   // rotate ring
    }

    // ---- reduce partials over the 16 col-lanes; one store per (row, wx) ----
    const size_t plane = (size_t)(blockIdx.x * 4 + wx) * (size_t)Ntot;
    #pragma unroll
    for (int m = 0; m < 4; ++m) {
        #pragma unroll
        for (int r = 0; r < 4; ++r) {
            float v = p[m][r];
            v += __shfl_xor(v, 1, 64);
            v += __shfl_xor(v, 2, 64);
            v += __shfl_xor(v, 4, 64);
            v += __shfl_xor(v, 8, 64);
            if (lr == 0)
                partials[plane + brow + wy * 64 + m * 16 + kg * 4 + r] = v;
        }
    }
}

// Per-row finish: rep_i = (sum of planes)/N, loss term, att; block-reduce the
// three sums -> blocksums[3][64]. 64 blocks x 256 threads, one i per thread.
__global__ __launch_bounds__(256) void rowsum_kernel(
    const float* __restrict__ partials, const float* __restrict__ att,
    float* __restrict__ blocksums, int N)
{
    __shared__ float sm[3][4];
    const int i = blockIdx.x * 256 + threadIdx.x;
    const float inv = 1.0f / (float)N;
    float s = 0.f;
    #pragma unroll
    for (int pl = 0; pl < 4 * NCHUNK; ++pl)
        s += partials[(size_t)pl * N + i];
    const float rp = s * inv;
    const float at = att[i];
    float ls = log1pf(rp / (at + EPS));
    float sa = at;
    float sr = rp;
    #pragma unroll
    for (int m = 32; m; m >>= 1) {
        ls += __shfl_xor(ls, m, 64);
        sa += __shfl_xor(sa, m, 64);
        sr += __shfl_xor(sr, m, 64);
    }
    const int w = threadIdx.x >> 6, lane = threadIdx.x & 63;
    if (lane == 0) { sm[0][w] = ls; sm[1][w] = sa; sm[2][w] = sr; }
    __syncthreads();
    if (threadIdx.x < 3) {
        const float v = sm[threadIdx.x][0] + sm[threadIdx.x][1]
                      + sm[threadIdx.x][2] + sm[threadIdx.x][3];
        blocksums[threadIdx.x * 64 + blockIdx.x] = v;
    }
}

// Final: 3 waves, wave w reduces blocksums[w][0..63] -> out[w] / N.
__global__ __launch_bounds__(192) void final_kernel(
    const float* __restrict__ blocksums, float* __restrict__ out, int N)
{
    const int w = threadIdx.x >> 6;      // 0..2 output component
    const int lane = threadIdx.x & 63;
    float v = blocksums[w * 64 + lane];
    #pragma unroll
    for (int m = 32; m; m >>= 1) v += __shfl_xor(v, m, 64);
    if (lane == 0) out[w] = v / (float)N;
}

extern "C" void kernel_launch(void* const* d_in, const int* in_sizes, int n_in,
                              void* d_out, int out_size, void* d_ws, size_t ws_size,
                              hipStream_t stream)
{
    const float* X1 = (const float*)d_in[0];
    const float* X2 = (const float*)d_in[1];
    const int N = in_sizes[0] / D_DIM;   // 16384
    float* out = (float*)d_out;

    char* ws = (char*)d_ws;
    ushort* B1 = (ushort*)ws;                                  // N*128*2 B
    ushort* B2 = (ushort*)(ws + (size_t)N * D_DIM * 2);        // N*128*2 B
    float* sq1n = (float*)(ws + (size_t)N * D_DIM * 4);
    float* sq2 = sq1n + N;
    float* att = sq2 + N;
    float* partials = att + N;           // [4*NCHUNK][N] = 2 MB
    float* blocksums = partials + (size_t)4 * NCHUNK * N;   // 192 floats
    // total ws use ~= 10.4 MB

    prep_kernel<<<N / 4, 256, 0, stream>>>(X1, X2, B1, B2, sq1n, sq2, att);
    dim3 grid(NCHUNK, N / BM);
    cross_kernel<<<grid, 512, 0, stream>>>(B1, B2, sq1n, sq2, partials, N);
    rowsum_kernel<<<N / 256, 256, 0, stream>>>(partials, att, blocksums, N);
    final_kernel<<<1, 192, 0, stream>>>(blocksums, out, N);
}